// Round 1
// baseline (267.892 us; speedup 1.0000x reference)
//
#include <hip/hip_runtime.h>
#include <hip/hip_bf16.h>
#include <cstdint>

#define B_ 2
#define S_ 4096
#define E_ 768
#define H_ 12
#define D_ 64

typedef __bf16 bf16x8 __attribute__((ext_vector_type(8)));
typedef float f32x4 __attribute__((ext_vector_type(4)));
typedef unsigned short ushort8 __attribute__((ext_vector_type(8)));
typedef unsigned short ushort4v __attribute__((ext_vector_type(4)));

static __device__ __forceinline__ unsigned short f2bf(float f) {
    union { float f; uint32_t u; } v; v.f = f;
    uint32_t u = v.u;
    u += 0x7FFFu + ((u >> 16) & 1u);
    return (unsigned short)(u >> 16);
}

// ---------------- convert hidden_states fp32 -> bf16 ----------------
__global__ void cvt_x(const float* __restrict__ x, unsigned short* __restrict__ xb, int n4) {
    int i = blockIdx.x * blockDim.x + threadIdx.x;
    int stride = gridDim.x * blockDim.x;
    for (; i < n4; i += stride) {
        float4 f = ((const float4*)x)[i];
        ushort4v o;
        o.x = f2bf(f.x); o.y = f2bf(f.y); o.z = f2bf(f.z); o.w = f2bf(f.w);
        ((ushort4v*)xb)[i] = o;
    }
}

// ---------------- convert + transpose weights: WT[n][k] = W[k][n], bf16 ----------------
__global__ void cvt_w(const float* __restrict__ Wq, const float* __restrict__ Wk,
                      const float* __restrict__ Wv, unsigned short* __restrict__ wt) {
    __shared__ float tl[32][33];
    int wsel = blockIdx.z;
    const float* src = wsel == 0 ? Wq : (wsel == 1 ? Wk : Wv);
    int tx = threadIdx.x, ty = threadIdx.y;
    int n0 = blockIdx.x * 32, k0 = blockIdx.y * 32;
    for (int i = 0; i < 4; i++) {
        int k = k0 + ty + i * 8;
        tl[ty + i * 8][tx] = src[(size_t)k * E_ + n0 + tx];
    }
    __syncthreads();
    unsigned short* dst = wt + (size_t)wsel * E_ * E_;
    for (int i = 0; i < 4; i++) {
        int n = n0 + ty + i * 8;
        dst[(size_t)n * E_ + k0 + tx] = f2bf(tl[tx][ty + i * 8]);
    }
}

// ---------------- QKV GEMM: out[w][m][n] = bf16((X @ W_w + b_w) * scale_w) ----------------
#define GM 128
#define GN 64
#define AST 56   // LDS A stride (elems) -> 112B rows, 16B aligned, ~2-way banks

__global__ __launch_bounds__(256) void qkv_gemm(const unsigned short* __restrict__ xb,
        const unsigned short* __restrict__ wt,
        const float* __restrict__ biasq, const float* __restrict__ biask,
        const float* __restrict__ biasv, unsigned short* __restrict__ qkv) {
    __shared__ unsigned short alds[GM * AST];
    int m0 = blockIdx.x * GM;
    int nblk = blockIdx.y * GN;          // 0..2304
    int wsel = nblk / E_;
    int nn0 = nblk % E_;
    const float* bias = wsel == 0 ? biasq : (wsel == 1 ? biask : biasv);
    float scale = wsel == 0 ? 0.125f : 1.0f;
    int t = threadIdx.x;
    int lane = t & 63, wv = t >> 6;
    int wm = wv >> 1, wn = wv & 1;
    int l15 = lane & 15, l4 = lane >> 4;

    f32x4 acc[4][2];
    for (int f = 0; f < 4; f++)
        for (int nf = 0; nf < 2; nf++)
            acc[f][nf] = (f32x4){0.f, 0.f, 0.f, 0.f};

    int srow = t >> 1;
    int scol = (t & 1) * 16;
    const unsigned short* xrow = xb + (size_t)(m0 + srow) * E_ + scol;
    unsigned short* sdst = alds + srow * AST + scol;
    const unsigned short* wbase = wt + (size_t)wsel * E_ * E_;

    for (int kk = 0; kk < E_; kk += 32) {
        ushort8 a0 = *(const ushort8*)(xrow + kk);
        ushort8 a1 = *(const ushort8*)(xrow + kk + 8);
        *(ushort8*)(sdst) = a0;
        *(ushort8*)(sdst + 8) = a1;
        __syncthreads();
        bf16x8 bfr[2];
        for (int nf = 0; nf < 2; nf++) {
            int nn = nn0 + wn * 32 + nf * 16 + l15;
            bfr[nf] = *(const bf16x8*)(wbase + (size_t)nn * E_ + kk + l4 * 8);
        }
        for (int f = 0; f < 4; f++) {
            bf16x8 afr = *(const bf16x8*)(alds + (wm * 64 + f * 16 + l15) * AST + l4 * 8);
            acc[f][0] = __builtin_amdgcn_mfma_f32_16x16x32_bf16(afr, bfr[0], acc[f][0], 0, 0, 0);
            acc[f][1] = __builtin_amdgcn_mfma_f32_16x16x32_bf16(afr, bfr[1], acc[f][1], 0, 0, 0);
        }
        __syncthreads();
    }
    for (int f = 0; f < 4; f++) {
        int row = m0 + wm * 64 + f * 16;
        for (int nf = 0; nf < 2; nf++) {
            int nn = nn0 + wn * 32 + nf * 16 + l15;
            float bb = bias[nn];
            for (int r = 0; r < 4; r++) {
                float v = (acc[f][nf][r] + bb) * scale;
                qkv[(size_t)wsel * 8192 * E_ + (size_t)(row + l4 * 4 + r) * E_ + nn] = f2bf(v);
            }
        }
    }
}

// ---------------- banded flash attention ----------------
#define PST 40
#define VST 40

__global__ __launch_bounds__(256) void attn(const unsigned short* __restrict__ qkv,
        const float* __restrict__ amask, float* __restrict__ out) {
    __shared__ unsigned short vt[4][64 * VST];
    __shared__ unsigned short pl[4][16 * PST];
    int qt = blockIdx.x;
    int h = blockIdx.y;
    int b = blockIdx.z;
    int t = threadIdx.x, lane = t & 63, wv = t >> 6;
    int l15 = lane & 15, l4 = lane >> 4;
    const unsigned short* qp = qkv;
    const unsigned short* kp = qkv + (size_t)8192 * E_;
    const unsigned short* vp = qkv + (size_t)2 * 8192 * E_;
    size_t rowbase = (size_t)b * S_;
    int hcol = h * D_;

    int q0 = qt * 64 + wv * 16;
    bf16x8 qf[2];
    {
        const unsigned short* qrow = qp + (rowbase + q0 + l15) * E_ + hcol;
        qf[0] = *(const bf16x8*)(qrow + l4 * 8);
        qf[1] = *(const bf16x8*)(qrow + 32 + l4 * 8);
    }
    float mrun[4], lrun[4];
    f32x4 oacc[4];
    for (int r = 0; r < 4; r++) { mrun[r] = -1e30f; lrun[r] = 0.f; }
    for (int nt = 0; nt < 4; nt++) oacc[nt] = (f32x4){0.f, 0.f, 0.f, 0.f};

    int kt0 = (q0 - 256) & ~31;
    unsigned short* vtl = (unsigned short*)vt[wv];
    unsigned short* pll = (unsigned short*)pl[wv];
    const float* amb = amask + (size_t)b * S_;

    for (int it = 0; it < 17; ++it) {
        int kg = kt0 + it * 32;
        // --- QK^T for 32 keys
        f32x4 s[2];
        for (int nt = 0; nt < 2; ++nt) {
            int key = kg + nt * 16 + l15;
            int keyc = min(max(key, 0), S_ - 1);
            const unsigned short* krow = kp + (rowbase + keyc) * E_ + hcol;
            bf16x8 kf0 = *(const bf16x8*)(krow + l4 * 8);
            bf16x8 kf1 = *(const bf16x8*)(krow + 32 + l4 * 8);
            f32x4 z = (f32x4){0.f, 0.f, 0.f, 0.f};
            z = __builtin_amdgcn_mfma_f32_16x16x32_bf16(qf[0], kf0, z, 0, 0, 0);
            s[nt] = __builtin_amdgcn_mfma_f32_16x16x32_bf16(qf[1], kf1, z, 0, 0, 0);
        }
        // --- stage V tile transposed into per-wave LDS
        {
            int key = kg + (lane & 31);
            int keyc = min(max(key, 0), S_ - 1);
            bool kvalid = (key >= 0) && (key < S_);
            const unsigned short* vrow = vp + (rowbase + keyc) * E_ + hcol;
            ushort8 zero8 = {0, 0, 0, 0, 0, 0, 0, 0};
            for (int i = 0; i < 4; i++) {
                int seg = (lane >> 5) + 2 * i;   // 0..7
                ushort8 vvec = kvalid ? *(const ushort8*)(vrow + seg * 8) : zero8;
                for (int j = 0; j < 8; j++)
                    vtl[(seg * 8 + j) * VST + (lane & 31)] = vvec[j];
            }
        }
        // --- mask + validity + online softmax
        float fmadd[2];
        int keyn[2];
        for (int nt = 0; nt < 2; nt++) {
            int key = kg + nt * 16 + l15;
            keyn[nt] = key;
            bool inr = (key >= 0) && (key < S_);
            float mval = inr ? amb[key] : 0.f;
            fmadd[nt] = (mval != 0.f) ? -10000.f : 0.f;
        }
        float sm[2][4];
        bool vmask[2][4];
        for (int nt = 0; nt < 2; nt++) {
            for (int r = 0; r < 4; r++) {
                int row = q0 + l4 * 4 + r;
                int key = keyn[nt];
                int dd = key - row;
                bool valid = (key >= 0) && (key < S_) && (dd <= 256) && (dd >= -256);
                vmask[nt][r] = valid;
                sm[nt][r] = valid ? (s[nt][r] + fmadd[nt]) : -1e30f;
            }
        }
        float mt[4];
        for (int r = 0; r < 4; r++) mt[r] = fmaxf(sm[0][r], sm[1][r]);
        for (int off = 1; off < 16; off <<= 1)
            for (int r = 0; r < 4; r++) mt[r] = fmaxf(mt[r], __shfl_xor(mt[r], off));
        float ptile[2][4], psum[4], sc[4];
        for (int r = 0; r < 4; r++) {
            float mnew = fmaxf(mrun[r], mt[r]);
            sc[r] = __expf(mrun[r] - mnew);
            mrun[r] = mnew;
            for (int nt = 0; nt < 2; nt++)
                ptile[nt][r] = vmask[nt][r] ? __expf(sm[nt][r] - mnew) : 0.f;
            psum[r] = ptile[0][r] + ptile[1][r];
        }
        for (int off = 1; off < 16; off <<= 1)
            for (int r = 0; r < 4; r++) psum[r] += __shfl_xor(psum[r], off);
        for (int r = 0; r < 4; r++) {
            lrun[r] = lrun[r] * sc[r] + psum[r];
            for (int nt = 0; nt < 4; nt++) oacc[nt][r] *= sc[r];
        }
        // --- P -> LDS (bf16)
        for (int nt = 0; nt < 2; nt++)
            for (int r = 0; r < 4; r++)
                pll[(l4 * 4 + r) * PST + nt * 16 + l15] = f2bf(ptile[nt][r]);
        // --- PV
        bf16x8 pa = *(const bf16x8*)(pll + l15 * PST + l4 * 8);
        for (int nt = 0; nt < 4; nt++) {
            bf16x8 vb = *(const bf16x8*)(vtl + (nt * 16 + l15) * VST + l4 * 8);
            oacc[nt] = __builtin_amdgcn_mfma_f32_16x16x32_bf16(pa, vb, oacc[nt], 0, 0, 0);
        }
    }
    // --- epilogue
    for (int r = 0; r < 4; r++) {
        int row = q0 + l4 * 4 + r;
        float inv = 1.0f / lrun[r];
        if (amb[row] < 0.f) inv = 0.f;
        for (int nt = 0; nt < 4; nt++) {
            out[((size_t)b * S_ + row) * E_ + hcol + nt * 16 + l15] = oacc[nt][r] * inv;
        }
    }
}

extern "C" void kernel_launch(void* const* d_in, const int* in_sizes, int n_in,
                              void* d_out, int out_size, void* d_ws, size_t ws_size,
                              hipStream_t stream) {
    const float* hs = (const float*)d_in[0];
    const float* am = (const float*)d_in[1];
    const float* Wq = (const float*)d_in[2];
    const float* bq = (const float*)d_in[3];
    const float* Wk = (const float*)d_in[4];
    const float* bk = (const float*)d_in[5];
    const float* Wv = (const float*)d_in[6];
    const float* bv = (const float*)d_in[7];
    float* out = (float*)d_out;
    unsigned short* xb  = (unsigned short*)d_ws;                  // 8192*768 bf16
    unsigned short* wtp = xb + (size_t)8192 * E_;                 // 3*768*768 bf16
    unsigned short* qkv = wtp + (size_t)3 * E_ * E_;              // 3*8192*768 bf16

    hipLaunchKernelGGL(cvt_x, dim3(2048), dim3(256), 0, stream, hs, xb, 8192 * E_ / 4);
    hipLaunchKernelGGL(cvt_w, dim3(24, 24, 3), dim3(32, 8), 0, stream, Wq, Wk, Wv, wtp);
    hipLaunchKernelGGL(qkv_gemm, dim3(64, 36), dim3(256), 0, stream, xb, wtp, bq, bk, bv, qkv);
    hipLaunchKernelGGL(attn, dim3(64, 12, 2), dim3(256), 0, stream, qkv, am, out);
}